// Round 1
// baseline (89.867 us; speedup 1.0000x reference)
//
#include <hip/hip_runtime.h>

// GroupAvgPool1d: x [B,N,C] fp32, y [B,N] int group ids (y<0 dropped), G groups.
// Outputs concatenated in d_out: feature [B,G,C] fp32, mask [B,G] (0.0/1.0).
// Shapes fixed by setup_inputs(): B=16, N=8192, C=64, G=512.

#define B_ 16
#define N_ 8192
#define C_ 64     // == wavefront lanes used as channel index
#define G_ 512

// One wave (64 lanes) per (b,g) output row. lane = channel c.
// Scan y[b,:] in int4 chunks (256 ids / wave-iteration), ballot for matches,
// then all 64 lanes cooperatively accumulate x[b,n,:] (256B coalesced load).
// No atomics, deterministic, every output element written exactly once.
__global__ __launch_bounds__(256) void gap_gather(const float* __restrict__ x,
                                                  const int* __restrict__ y,
                                                  float* __restrict__ feature,
                                                  float* __restrict__ maskout) {
    const int lane = threadIdx.x & 63;
    const int wid  = (blockIdx.x * blockDim.x + threadIdx.x) >> 6;  // 0..B*G-1
    const int b = wid >> 9;          // wid / G_
    const int g = wid & (G_ - 1);    // wid % G_

    const int*   yb = y + b * N_;
    const float* xb = x + (size_t)b * (size_t)(N_ * C_);

    float acc = 0.0f;
    int   cnt = 0;

    for (int n0 = 0; n0 < N_; n0 += 256) {
        // lane loads 4 consecutive ids: n = n0 + lane*4 + j
        const int4 yv = *reinterpret_cast<const int4*>(yb + n0 + lane * 4);
        unsigned long long m0 = __ballot(yv.x == g);
        unsigned long long m1 = __ballot(yv.y == g);
        unsigned long long m2 = __ballot(yv.z == g);
        unsigned long long m3 = __ballot(yv.w == g);
        cnt += __popcll(m0) + __popcll(m1) + __popcll(m2) + __popcll(m3);
        // wave-uniform bit loops (mask is identical across lanes -> no divergence)
        while (m0) { int l = __builtin_ctzll(m0); m0 &= m0 - 1;
                     acc += xb[(size_t)(n0 + l * 4 + 0) * C_ + lane]; }
        while (m1) { int l = __builtin_ctzll(m1); m1 &= m1 - 1;
                     acc += xb[(size_t)(n0 + l * 4 + 1) * C_ + lane]; }
        while (m2) { int l = __builtin_ctzll(m2); m2 &= m2 - 1;
                     acc += xb[(size_t)(n0 + l * 4 + 2) * C_ + lane]; }
        while (m3) { int l = __builtin_ctzll(m3); m3 &= m3 - 1;
                     acc += xb[(size_t)(n0 + l * 4 + 3) * C_ + lane]; }
    }

    feature[((size_t)b * G_ + g) * C_ + lane] = acc * (1.0f / (float)N_);
    if (lane == 0) maskout[b * G_ + g] = (cnt > 0) ? 1.0f : 0.0f;
}

extern "C" void kernel_launch(void* const* d_in, const int* in_sizes, int n_in,
                              void* d_out, int out_size, void* d_ws, size_t ws_size,
                              hipStream_t stream) {
    const float* x = (const float*)d_in[0];
    const int*   y = (const int*)d_in[1];
    float* feature = (float*)d_out;                      // B*G*C floats
    float* maskout = (float*)d_out + (size_t)B_ * G_ * C_; // B*G floats

    const int total_waves = B_ * G_;          // 8192 waves
    const int block = 256;                    // 4 waves/block
    const int grid  = total_waves * 64 / block; // 2048 blocks
    gap_gather<<<grid, block, 0, stream>>>(x, y, feature, maskout);
}

// Round 2
// 88.137 us; speedup vs baseline: 1.0196x; 1.0196x over previous
//
#include <hip/hip_runtime.h>

// GroupAvgPool1d: x [B,N,C] fp32, y [B,N] int group ids, G groups.
// d_out = feature [B,G,C] fp32 ++ mask [B,G] (0.0/1.0).
// Shapes fixed: B=16, N=8192, C=64, G=512.
//
// v2: block = 4 waves handles (b, g0..g0+3). y chunks staged via LDS once per
// block (4x less y traffic, low-latency ds_read scan), register-prefetched one
// chunk ahead so global y latency overlaps processing. x gathered coalesced
// (256B/row, read exactly once). No atomics, deterministic.

#define B_ 16
#define N_ 8192
#define C_ 64
#define G_ 512
#define CHUNK 1024            // ids staged per iteration (4 KB LDS)
#define NCHUNK (N_ / CHUNK)   // 8

__global__ __launch_bounds__(256, 8)
void gap_gather2(const float* __restrict__ x, const int* __restrict__ y,
                 float* __restrict__ feature, float* __restrict__ maskout) {
    const int tid  = threadIdx.x;
    const int lane = tid & 63;
    const int wave = tid >> 6;
    const int blk  = blockIdx.x;            // 0 .. B*G/4 - 1
    const int b    = blk >> 7;              // / (G/4 = 128)
    const int g    = ((blk & 127) << 2) + wave;

    const int*   yb = y + b * N_;
    const float* xb = x + (size_t)b * (size_t)(N_ * C_);

    __shared__ int sy[CHUNK];

    float acc = 0.0f;
    int   cnt = 0;

    // prefetch chunk 0 into registers (one int4 per thread = 1024 ids/block)
    int4 pre = *reinterpret_cast<const int4*>(yb + tid * 4);

    for (int ch = 0; ch < NCHUNK; ++ch) {
        __syncthreads();                    // all waves done reading sy
        *reinterpret_cast<int4*>(&sy[tid * 4]) = pre;
        __syncthreads();                    // sy ready
        if (ch + 1 < NCHUNK)                // prefetch next chunk; latency
            pre = *reinterpret_cast<const int4*>(yb + (ch + 1) * CHUNK + tid * 4);
                                            // overlaps the processing below
        const int nbase = ch * CHUNK;
        #pragma unroll
        for (int sub = 0; sub < CHUNK / 256; ++sub) {
            // lane reads 4 consecutive ids: conflict-free b128 (stride 16B)
            const int4 yv = *reinterpret_cast<const int4*>(&sy[sub * 256 + lane * 4]);
            unsigned long long m0 = __ballot(yv.x == g);
            unsigned long long m1 = __ballot(yv.y == g);
            unsigned long long m2 = __ballot(yv.z == g);
            unsigned long long m3 = __ballot(yv.w == g);
            cnt += __popcll(m0) + __popcll(m1) + __popcll(m2) + __popcll(m3);
            const int sb = nbase + sub * 256;
            // wave-uniform bit loops; each match = one coalesced 256B x-row load
            while (m0) { int l = __builtin_ctzll(m0); m0 &= m0 - 1;
                         acc += xb[(size_t)(sb + l * 4 + 0) * C_ + lane]; }
            while (m1) { int l = __builtin_ctzll(m1); m1 &= m1 - 1;
                         acc += xb[(size_t)(sb + l * 4 + 1) * C_ + lane]; }
            while (m2) { int l = __builtin_ctzll(m2); m2 &= m2 - 1;
                         acc += xb[(size_t)(sb + l * 4 + 2) * C_ + lane]; }
            while (m3) { int l = __builtin_ctzll(m3); m3 &= m3 - 1;
                         acc += xb[(size_t)(sb + l * 4 + 3) * C_ + lane]; }
        }
    }

    feature[((size_t)b * G_ + g) * C_ + lane] = acc * (1.0f / (float)N_);
    if (lane == 0) maskout[b * G_ + g] = (cnt > 0) ? 1.0f : 0.0f;
}

extern "C" void kernel_launch(void* const* d_in, const int* in_sizes, int n_in,
                              void* d_out, int out_size, void* d_ws, size_t ws_size,
                              hipStream_t stream) {
    const float* x = (const float*)d_in[0];
    const int*   y = (const int*)d_in[1];
    float* feature = (float*)d_out;                        // B*G*C floats
    float* maskout = (float*)d_out + (size_t)B_ * G_ * C_; // B*G floats

    const int grid = B_ * (G_ / 4);   // 2048 blocks x 256 threads (4 waves)
    gap_gather2<<<grid, 256, 0, stream>>>(x, y, feature, maskout);
}